// Round 8
// baseline (945.067 us; speedup 1.0000x reference)
//
#include <hip/hip_runtime.h>

// ---- problem constants ----
#define NXg    512
#define Sg     262144          // 512*512
#define NFRg   60
// ---- temporal blocking ----
#define Kg     8               // steps per chunk
#define NCHUNK 30              // 240 / 8
#define Tg     32              // owned tile (32x32), 16x16 tiles = 256 blocks
#define Eg     48              // extended tile (T + 2K)
#define EJP    50              // padded LDS row stride in float2 (400 B)
#define NSEGR  12              // 4-cell segments per row
#define NTHR   576             // 48 rows * 12 segments = 9 waves
#define FLAGPAD 16             // ints per flag slot (64 B)

// ws layout (float2 units): Gc0 | Gp0 | Gc1 | Gp1 | flags
// Gc*/Gp* are parity-alternating publish buffers (global cell coords).
#define WS_NEEDED (4ull * Sg * 8ull + 256ull * FLAGPAD * 4ull)

// ---------------- shared cell-update macro ----------------
#define CELLSTEP(nv, NW, N, NE, Wt, C, Et, SW, S, SE, P, GF, INB)            \
{                                                                            \
    const float sxx_x = N.x + S.x - 2.0f * C.x;                              \
    const float syy_x = Wt.x + Et.x - 2.0f * C.x;                            \
    const float sxy_x = 0.25f * (NW.x - NE.x - SW.x + SE.x);                 \
    const float sxx_y = N.y + S.y - 2.0f * C.y;                              \
    const float syy_y = Wt.y + Et.y - 2.0f * C.y;                            \
    const float sxy_y = 0.25f * (NW.y - NE.y - SW.y + SE.y);                 \
    const float lux = kc11 * sxx_x + kc66 * syy_x + kc1266 * sxy_y           \
                    + kc16x2 * sxy_x + kc16 * sxx_y + kc26 * syy_y;          \
    const float luy = kc66 * sxx_y + kc22 * syy_y + kc1266 * sxy_x           \
                    + kc16 * sxx_x + kc26 * syy_x + kc26x2 * sxy_y           \
                    + fa * GF;                                               \
    float vx = 2.0f * C.x - P.x + lux;                                       \
    float vy = 2.0f * C.y - P.y + luy;                                       \
    vx = INB ? vx : 0.0f;                                                    \
    vy = INB ? vy : 0.0f;                                                    \
    nv = make_float2(vx, vy);                                                \
}

__global__ __launch_bounds__(256)
void cfrp_zero_flags(int* __restrict__ flags)
{
    flags[(int)threadIdx.x * FLAGPAD] = 0;
}

// =====================================================================
// Persistent cooperative kernel: all 30 chunks in one dispatch.
// Inter-block sync = per-block chunk counters (device-scope atomics) +
// release/acquire fences; each block waits only on its 8 neighbors.
// =====================================================================
__global__ __launch_bounds__(NTHR)
void cfrp_persist(const float* __restrict__ lc11, const float* __restrict__ lc22,
                  const float* __restrict__ lc12, const float* __restrict__ lc16,
                  const float* __restrict__ lc26, const float* __restrict__ lc66,
                  const float* __restrict__ rho_p, const float* __restrict__ sig,
                  const float* __restrict__ gauss, float* __restrict__ out,
                  float2* __restrict__ ws)
{
    __shared__ float2 sf[2][Eg * EJP];

    float2* Gc0 = ws;
    float2* Gp0 = ws + Sg;
    float2* Gc1 = ws + 2 * (size_t)Sg;
    float2* Gp1 = ws + 3 * (size_t)Sg;
    int*  flags = (int*)(ws + 4 * (size_t)Sg);

    const int tid = (int)threadIdx.x;
    // XCD-affinity: XCD q (= wg&7 round-robin heuristic) owns tile-rows 2q..2q+1.
    const int w  = (int)blockIdx.x;
    const int q  = w & 7;
    const int r_ = w >> 3;                 // 0..31
    const int ti = q * 2 + (r_ >> 4);      // 0..15
    const int tj = r_ & 15;                // 0..15
    const int oi = ti * Tg - Kg;
    const int oj = tj * Tg - Kg;
    const int myfl = (ti * 16 + tj) * FLAGPAD;

    // uniform material constants
    const float C11 = fminf(fmaxf(expf(lc11[0]), 1e9f), 1e13f);
    const float C22 = fminf(fmaxf(expf(lc22[0]), 1e9f), 1e13f);
    const float C12 = fminf(fmaxf(expf(lc12[0]), 1e9f), 1e13f);
    const float C16 = fminf(fmaxf(expf(lc16[0]), 1e9f), 1e13f);
    const float C26 = fminf(fmaxf(expf(lc26[0]), 1e9f), 1e13f);
    const float C66 = fminf(fmaxf(expf(lc66[0]), 1e9f), 1e13f);
    const float rh   = rho_p[0];
    const float dt2  = 2.5e-15f;
    const float kk   = dt2 * 1e6f / rh;
    const float kc11 = kk * C11, kc22 = kk * C22, kc66 = kk * C66;
    const float kc16 = kk * C16, kc26 = kk * C26;
    const float kc1266 = kk * (C12 + C66);
    const float kc16x2 = 2.0f * kc16;
    const float kc26x2 = 2.0f * kc26;
    const float gsc = dt2 / rh;

    // zero LDS (both buffers incl. pads) — initial field is zero
    {
        float2* sflat = &sf[0][0];
        #pragma unroll 1
        for (int k = tid; k < 2 * Eg * EJP; k += NTHR)
            sflat[k] = make_float2(0.f, 0.f);
    }

    // per-segment setup (thread owns a 1x4 horizontal strip)
    const int  srow = tid / NSEGR;
    const int  scol = tid - srow * NSEGR;
    const bool act  = (srow >= 1) && (srow <= Eg - 2);
    const int  c0   = scol * 4;
    const int  gi   = oi + srow;
    const int  gj0  = oj + c0;
    const int  idxC = srow * EJP + c0;
    const bool rin  = (unsigned)gi < NXg;
    const bool inb0 = rin && ((unsigned)(gj0 + 0) < NXg);
    const bool inb1 = rin && ((unsigned)(gj0 + 1) < NXg);
    const bool inb2 = rin && ((unsigned)(gj0 + 2) < NXg);
    const bool inb3 = rin && ((unsigned)(gj0 + 3) < NXg);
    const bool own  = (srow >= Kg) && (srow < Kg + Tg) && (scol >= 2) && (scol <= 9);
    const int  go0  = gi * NXg + gj0;

    float  gf0 = 0.f, gf1 = 0.f, gf2 = 0.f, gf3 = 0.f;
    if (act && rin && ((unsigned)gj0 < NXg)) {
        const float4 g = *(const float4*)&gauss[go0];
        gf0 = g.x * gsc; gf1 = g.y * gsc; gf2 = g.z * gsc; gf3 = g.w * gsc;
    }
    float2 pv0 = {0.f,0.f}, pv1 = {0.f,0.f}, pv2 = {0.f,0.f}, pv3 = {0.f,0.f};
    float2 cv0 = {0.f,0.f}, cv1 = {0.f,0.f}, cv2 = {0.f,0.f}, cv3 = {0.f,0.f};

    __syncthreads();

    #pragma unroll 1
    for (int c = 0; c < NCHUNK; ++c) {
        if (c > 0) {
            // ---- wait for 8 neighbors to have published chunk c-1 ----
            if (tid < 8) {
                const int k2 = (tid < 4) ? tid : (tid + 1);   // skip center
                const int dr = k2 / 3 - 1, dc = k2 - (k2 / 3) * 3 - 1;
                const int nti = ti + dr, ntj = tj + dc;
                if ((unsigned)nti < 16u && (unsigned)ntj < 16u) {
                    int* fp = &flags[(nti * 16 + ntj) * FLAGPAD];
                    while (atomicAdd(fp, 0) < c)      // LLC-coherent read
                        __builtin_amdgcn_s_sleep(2);
                }
            }
            __syncthreads();
            if (tid == 0) __threadfence();   // acquire: invalidate stale L2
            __syncthreads();

            const float2* Gc = (c & 1) ? Gc1 : Gc0;
            const float2* Gp = (c & 1) ? Gp1 : Gp0;

            // ---- re-stage ring (ext minus owned interior) into sf[0] ----
            #pragma unroll
            for (int s = 0; s < 2; ++s) {
                const int p  = tid + s * NTHR;      // 0..1151 cell pairs
                const int rr = p / 24;
                const int cp = (p - rr * 24) * 2;   // even ext col
                const bool skip = (rr >= Kg) && (rr < Kg + Tg) &&
                                  (cp >= Kg) && (cp < Kg + Tg);
                if (!skip) {
                    const int gi2 = oi + rr, gj2 = oj + cp;
                    float4 v = make_float4(0.f, 0.f, 0.f, 0.f);
                    if (((unsigned)gi2 < NXg) && ((unsigned)gj2 < NXg))
                        v = *(const float4*)&Gc[gi2 * NXg + gj2];
                    *(float4*)&sf[0][rr * EJP + cp] = v;
                }
            }
            // ring threads reload prev from neighbors' publish
            if (act && !own) {
                pv0 = pv1 = pv2 = pv3 = make_float2(0.f, 0.f);
                if (rin) {
                    if ((unsigned)gj0 < NXg) {
                        const float4 t = *(const float4*)&Gp[go0];
                        pv0 = make_float2(t.x, t.y); pv1 = make_float2(t.z, t.w);
                    }
                    if ((unsigned)(gj0 + 2) < NXg) {
                        const float4 t = *(const float4*)&Gp[go0 + 2];
                        pv2 = make_float2(t.x, t.y); pv3 = make_float2(t.z, t.w);
                    }
                }
            }
            __syncthreads();
            // ring threads reload cur from freshly staged LDS
            if (act && !own) {
                const float4 a = *(const float4*)&sf[0][idxC];
                const float4 b = *(const float4*)&sf[0][idxC + 2];
                cv0 = make_float2(a.x, a.y); cv1 = make_float2(a.z, a.w);
                cv2 = make_float2(b.x, b.y); cv3 = make_float2(b.z, b.w);
            }
        }

        // ---- 8 timesteps in LDS (double-buffered, 1 barrier/step) ----
        const float2* cur = sf[0];
        float2*       nxt = sf[1];
        #pragma unroll
        for (int st = 0; st < Kg; ++st) {
            const float fa = sig[c * Kg + st];
            if (act) {
                const int iT = idxC - EJP;
                const int iB = idxC + EJP;
                const float4 t01 = *(const float4*)&cur[iT];
                const float4 t23 = *(const float4*)&cur[iT + 2];
                const float2 twv = cur[iT - 1];
                const float2 tev = cur[iT + 4];
                const float4 b01 = *(const float4*)&cur[iB];
                const float4 b23 = *(const float4*)&cur[iB + 2];
                const float2 bwv = cur[iB - 1];
                const float2 bev = cur[iB + 4];
                const float2 wmv = cur[idxC - 1];
                const float2 emv = cur[idxC + 4];

                const float2 ta0 = twv, ta1 = make_float2(t01.x, t01.y),
                             ta2 = make_float2(t01.z, t01.w),
                             ta3 = make_float2(t23.x, t23.y),
                             ta4 = make_float2(t23.z, t23.w), ta5 = tev;
                const float2 ba0 = bwv, ba1 = make_float2(b01.x, b01.y),
                             ba2 = make_float2(b01.z, b01.w),
                             ba3 = make_float2(b23.x, b23.y),
                             ba4 = make_float2(b23.z, b23.w), ba5 = bev;

                float2 nv0, nv1, nv2, nv3;
                CELLSTEP(nv0, ta0, ta1, ta2, wmv, cv0, cv1, ba0, ba1, ba2, pv0, gf0, inb0)
                CELLSTEP(nv1, ta1, ta2, ta3, cv0, cv1, cv2, ba1, ba2, ba3, pv1, gf1, inb1)
                CELLSTEP(nv2, ta2, ta3, ta4, cv1, cv2, cv3, ba2, ba3, ba4, pv2, gf2, inb2)
                CELLSTEP(nv3, ta3, ta4, ta5, cv2, cv3, emv, ba3, ba4, ba5, pv3, gf3, inb3)

                pv0 = cv0; pv1 = cv1; pv2 = cv2; pv3 = cv3;
                cv0 = nv0; cv1 = nv1; cv2 = nv2; cv3 = nv3;

                *(float4*)&nxt[idxC]     = make_float4(cv0.x, cv0.y, cv1.x, cv1.y);
                *(float4*)&nxt[idxC + 2] = make_float4(cv2.x, cv2.y, cv3.x, cv3.y);

                if (((st & 3) == 0) && own) {      // frames at st = 0, 4
                    const int fr = (c * Kg + st) >> 2;
                    *(float4*)&out[fr * Sg + go0] =
                        make_float4(cv0.x, cv1.x, cv2.x, cv3.x);
                    *(float4*)&out[(fr + NFRg) * Sg + go0] =
                        make_float4(cv0.y, cv1.y, cv2.y, cv3.y);
                }
            }
            __syncthreads();
            float2* tmp = (float2*)cur; cur = nxt; nxt = tmp;
        }

        // ---- publish owned tile (cur+prev) to parity (c+1)&1, flag ----
        {
            float2* Pc = ((c + 1) & 1) ? Gc1 : Gc0;
            float2* Pp = ((c + 1) & 1) ? Gp1 : Gp0;
            if (own) {
                *(float4*)&Pc[go0]     = make_float4(cv0.x, cv0.y, cv1.x, cv1.y);
                *(float4*)&Pc[go0 + 2] = make_float4(cv2.x, cv2.y, cv3.x, cv3.y);
                *(float4*)&Pp[go0]     = make_float4(pv0.x, pv0.y, pv1.x, pv1.y);
                *(float4*)&Pp[go0 + 2] = make_float4(pv2.x, pv2.y, pv3.x, pv3.y);
            }
            __syncthreads();                       // drain all publish stores
            if (tid == 0) {
                __threadfence();                   // release: L2 -> LLC
                atomicExch(&flags[myfl], c + 1);   // device-scope flag
            }
        }
    }
}

// =====================================================================
// Fallback (R7 path): per-chunk kernels, used only if ws is too small
// for the parity buffers + flags.
// =====================================================================
__global__ __launch_bounds__(512)
void cfrp_init(float4* __restrict__ ws4)
{
    const int gt = (int)blockIdx.x * 512 + (int)threadIdx.x;  // 262144
    ws4[gt] = make_float4(0.f, 0.f, 0.f, 0.f);
}

__global__ __launch_bounds__(NTHR)
void cfrp_chunk(const float* __restrict__ lc11, const float* __restrict__ lc22,
                const float* __restrict__ lc12, const float* __restrict__ lc16,
                const float* __restrict__ lc26, const float* __restrict__ lc66,
                const float* __restrict__ rho_p, const float* __restrict__ sig,
                const float* __restrict__ gauss, float* __restrict__ out,
                const float2* __restrict__ gcur, const float2* __restrict__ gprev,
                float2* __restrict__ ncur, float2* __restrict__ nprev,
                int TB)
{
    __shared__ float2 sf[2][Eg * EJP];

    const int tid = (int)threadIdx.x;
    const int w  = (int)blockIdx.x;
    const int q  = w & 7;
    const int r_ = w >> 3;
    const int ti = q * 2 + (r_ >> 4);
    const int tj = r_ & 15;
    const int oi = ti * Tg - Kg;
    const int oj = tj * Tg - Kg;

    const float C11 = fminf(fmaxf(expf(lc11[0]), 1e9f), 1e13f);
    const float C22 = fminf(fmaxf(expf(lc22[0]), 1e9f), 1e13f);
    const float C12 = fminf(fmaxf(expf(lc12[0]), 1e9f), 1e13f);
    const float C16 = fminf(fmaxf(expf(lc16[0]), 1e9f), 1e13f);
    const float C26 = fminf(fmaxf(expf(lc26[0]), 1e9f), 1e13f);
    const float C66 = fminf(fmaxf(expf(lc66[0]), 1e9f), 1e13f);
    const float rh   = rho_p[0];
    const float dt2  = 2.5e-15f;
    const float kk   = dt2 * 1e6f / rh;
    const float kc11 = kk * C11, kc22 = kk * C22, kc66 = kk * C66;
    const float kc16 = kk * C16, kc26 = kk * C26;
    const float kc1266 = kk * (C12 + C66);
    const float kc16x2 = 2.0f * kc16;
    const float kc26x2 = 2.0f * kc26;
    const float gsc = dt2 / rh;

    #pragma unroll
    for (int s = 0; s < 2; ++s) {
        const int p  = tid + s * NTHR;
        const int rr = p / 24;
        const int cp = (p - rr * 24) * 2;
        const int gi = oi + rr;
        const int gj = oj + cp;
        float4 v = make_float4(0.f, 0.f, 0.f, 0.f);
        if (((unsigned)gi < NXg) && ((unsigned)gj < NXg))
            v = *(const float4*)&gcur[gi * NXg + gj];
        const int li = rr * EJP + cp;
        *(float4*)&sf[0][li] = v;
        *(float4*)&sf[1][li] = v;
    }
    if (tid < Eg) {
        const int li = tid * EJP + Eg;
        *(float4*)&sf[0][li] = make_float4(0.f, 0.f, 0.f, 0.f);
        *(float4*)&sf[1][li] = make_float4(0.f, 0.f, 0.f, 0.f);
    }

    const int  srow = tid / NSEGR;
    const int  scol = tid - srow * NSEGR;
    const bool act  = (srow >= 1) && (srow <= Eg - 2);
    const int  c0   = scol * 4;
    const int  gi   = oi + srow;
    const int  gj0  = oj + c0;
    const int  idxC = srow * EJP + c0;
    const bool rin  = (unsigned)gi < NXg;
    const bool inb0 = rin && ((unsigned)(gj0 + 0) < NXg);
    const bool inb1 = rin && ((unsigned)(gj0 + 1) < NXg);
    const bool inb2 = rin && ((unsigned)(gj0 + 2) < NXg);
    const bool inb3 = rin && ((unsigned)(gj0 + 3) < NXg);
    const bool own  = (srow >= Kg) && (srow < Kg + Tg) && (scol >= 2) && (scol <= 9);
    const int  go0  = gi * NXg + gj0;

    float2 pv0 = {0.f,0.f}, pv1 = {0.f,0.f}, pv2 = {0.f,0.f}, pv3 = {0.f,0.f};
    float  gf0 = 0.f, gf1 = 0.f, gf2 = 0.f, gf3 = 0.f;
    if (act && rin) {
        if ((unsigned)gj0 < NXg) {
            const float4 t = *(const float4*)&gprev[go0];
            pv0 = make_float2(t.x, t.y); pv1 = make_float2(t.z, t.w);
            const float4 g = *(const float4*)&gauss[go0];
            gf0 = g.x * gsc; gf1 = g.y * gsc; gf2 = g.z * gsc; gf3 = g.w * gsc;
        }
        if ((unsigned)(gj0 + 2) < NXg) {
            const float4 t = *(const float4*)&gprev[go0 + 2];
            pv2 = make_float2(t.x, t.y); pv3 = make_float2(t.z, t.w);
        }
    }
    __syncthreads();

    float2 cv0, cv1, cv2, cv3;
    {
        const float4 a = *(const float4*)&sf[0][idxC];
        const float4 b = *(const float4*)&sf[0][idxC + 2];
        cv0 = make_float2(a.x, a.y); cv1 = make_float2(a.z, a.w);
        cv2 = make_float2(b.x, b.y); cv3 = make_float2(b.z, b.w);
    }

    const float2* cur = sf[0];
    float2*       nxt = sf[1];

    #pragma unroll
    for (int st = 0; st < Kg; ++st) {
        const float fa = sig[TB + st];
        if (act) {
            const int iT = idxC - EJP;
            const int iB = idxC + EJP;
            const float4 t01 = *(const float4*)&cur[iT];
            const float4 t23 = *(const float4*)&cur[iT + 2];
            const float2 twv = cur[iT - 1];
            const float2 tev = cur[iT + 4];
            const float4 b01 = *(const float4*)&cur[iB];
            const float4 b23 = *(const float4*)&cur[iB + 2];
            const float2 bwv = cur[iB - 1];
            const float2 bev = cur[iB + 4];
            const float2 wmv = cur[idxC - 1];
            const float2 emv = cur[idxC + 4];

            const float2 ta0 = twv, ta1 = make_float2(t01.x, t01.y),
                         ta2 = make_float2(t01.z, t01.w),
                         ta3 = make_float2(t23.x, t23.y),
                         ta4 = make_float2(t23.z, t23.w), ta5 = tev;
            const float2 ba0 = bwv, ba1 = make_float2(b01.x, b01.y),
                         ba2 = make_float2(b01.z, b01.w),
                         ba3 = make_float2(b23.x, b23.y),
                         ba4 = make_float2(b23.z, b23.w), ba5 = bev;

            float2 nv0, nv1, nv2, nv3;
            CELLSTEP(nv0, ta0, ta1, ta2, wmv, cv0, cv1, ba0, ba1, ba2, pv0, gf0, inb0)
            CELLSTEP(nv1, ta1, ta2, ta3, cv0, cv1, cv2, ba1, ba2, ba3, pv1, gf1, inb1)
            CELLSTEP(nv2, ta2, ta3, ta4, cv1, cv2, cv3, ba2, ba3, ba4, pv2, gf2, inb2)
            CELLSTEP(nv3, ta3, ta4, ta5, cv2, cv3, emv, ba3, ba4, ba5, pv3, gf3, inb3)

            pv0 = cv0; pv1 = cv1; pv2 = cv2; pv3 = cv3;
            cv0 = nv0; cv1 = nv1; cv2 = nv2; cv3 = nv3;

            *(float4*)&nxt[idxC]     = make_float4(cv0.x, cv0.y, cv1.x, cv1.y);
            *(float4*)&nxt[idxC + 2] = make_float4(cv2.x, cv2.y, cv3.x, cv3.y);

            if (((st & 3) == 0) && own) {
                const int fr = (TB + st) >> 2;
                *(float4*)&out[fr * Sg + go0] =
                    make_float4(cv0.x, cv1.x, cv2.x, cv3.x);
                *(float4*)&out[(fr + NFRg) * Sg + go0] =
                    make_float4(cv0.y, cv1.y, cv2.y, cv3.y);
            }
        }
        __syncthreads();
        float2* tmp = (float2*)cur; cur = nxt; nxt = tmp;
    }

    if (own) {
        *(float4*)&ncur[go0]      = make_float4(cv0.x, cv0.y, cv1.x, cv1.y);
        *(float4*)&ncur[go0 + 2]  = make_float4(cv2.x, cv2.y, cv3.x, cv3.y);
        *(float4*)&nprev[go0]     = make_float4(pv0.x, pv0.y, pv1.x, pv1.y);
        *(float4*)&nprev[go0 + 2] = make_float4(pv2.x, pv2.y, pv3.x, pv3.y);
    }
}

extern "C" void kernel_launch(void* const* d_in, const int* in_sizes, int n_in,
                              void* d_out, int out_size, void* d_ws, size_t ws_size,
                              hipStream_t stream) {
    const float* lc11  = (const float*)d_in[0];
    const float* lc22  = (const float*)d_in[1];
    const float* lc12  = (const float*)d_in[2];
    const float* lc16  = (const float*)d_in[3];
    const float* lc26  = (const float*)d_in[4];
    const float* lc66  = (const float*)d_in[5];
    const float* rho_p = (const float*)d_in[6];
    const float* sig   = (const float*)d_in[7];
    const float* gauss = (const float*)d_in[8];
    float* out  = (float*)d_out;
    float2* ws2 = (float2*)d_ws;

    if (ws_size >= WS_NEEDED) {
        // persistent path: zero flags, then one cooperative dispatch
        int* flags = (int*)(ws2 + 4 * (size_t)Sg);
        hipLaunchKernelGGL(cfrp_zero_flags, dim3(1), dim3(256), 0, stream, flags);

        void* args[] = { (void*)&lc11, (void*)&lc22, (void*)&lc12, (void*)&lc16,
                         (void*)&lc26, (void*)&lc66, (void*)&rho_p, (void*)&sig,
                         (void*)&gauss, (void*)&out, (void*)&ws2 };
        hipLaunchCooperativeKernel((const void*)cfrp_persist, dim3(256),
                                   dim3(NTHR), args, 0, stream);
    } else {
        // fallback: proven R7 multi-dispatch path
        float2* Ac = ws2;           float2* Ap = ws2 + Sg;
        float2* Bc = ws2 + 2 * Sg;  float2* Bp = ws2 + 3 * Sg;

        hipLaunchKernelGGL(cfrp_init, dim3(512), dim3(512), 0, stream, (float4*)d_ws);

        for (int c = 0; c < NCHUNK; ++c) {
            float2 *rc, *rp, *wc, *wp;
            if (c & 1) { rc = Bc; rp = Bp; wc = Ac; wp = Ap; }
            else       { rc = Ac; rp = Ap; wc = Bc; wp = Bp; }
            hipLaunchKernelGGL(cfrp_chunk, dim3(256), dim3(NTHR), 0, stream,
                               lc11, lc22, lc12, lc16, lc26, lc66, rho_p, sig,
                               gauss, out, rc, rp, wc, wp, c * Kg);
        }
    }
}

// Round 9
// 580.929 us; speedup vs baseline: 1.6268x; 1.6268x over previous
//
#include <hip/hip_runtime.h>

// ---- problem constants ----
#define NXg    512
#define Sg     262144          // 512*512
#define NFRg   60
// ---- temporal blocking ----
#define Kg     8               // steps per chunk
#define NCHUNK 30              // 240 / 8
#define Tg     32              // owned tile (32x32), 16x16 tiles = 256 blocks
#define Eg     48              // extended tile (T + 2K)
#define Pg     52              // LDS row pitch in floats (208 B -> 2-way max)
#define PLANE  (Eg * Pg)       // 2496 floats per component plane
#define NSEGR  12              // 4-cell segments per row
#define NTHR   576             // 48 rows * 12 segments = 9 waves

// Zero the A-set state (4 planar float buffers = Sg float4 total).
// B-set is fully overwritten by chunk 0 before being read.
__global__ __launch_bounds__(512)
void cfrp_init(float4* __restrict__ ws4)
{
    const int gt = (int)blockIdx.x * 512 + (int)threadIdx.x;  // 262144
    ws4[gt] = make_float4(0.f, 0.f, 0.f, 0.f);
}

// one-cell update macro: 9 taps per component + prev + gauss
#define CELL(NXO, NYO, nwx,nnx,nex,wtx,ctx,etx,swx,ssx,sex,                  \
                       nwy,nny,ney,wty,cty,ety,swy,ssy,sey, PX,PY,GF)        \
{                                                                            \
    const float sxx_x = nnx + ssx - 2.0f * ctx;                              \
    const float syy_x = wtx + etx - 2.0f * ctx;                              \
    const float sxy_x = 0.25f * (nwx - nex - swx + sex);                     \
    const float sxx_y = nny + ssy - 2.0f * cty;                              \
    const float syy_y = wty + ety - 2.0f * cty;                              \
    const float sxy_y = 0.25f * (nwy - ney - swy + sey);                     \
    const float lux = kc11 * sxx_x + kc66 * syy_x + kc1266 * sxy_y           \
                    + kc16x2 * sxy_x + kc16 * sxx_y + kc26 * syy_y;          \
    const float luy = kc66 * sxx_y + kc22 * syy_y + kc1266 * sxy_x           \
                    + kc16 * sxx_x + kc26 * syy_x + kc26x2 * sxy_y           \
                    + fa * GF;                                               \
    NXO = 2.0f * ctx - PX + lux;                                             \
    NYO = 2.0f * cty - PY + luy;                                             \
}

// Advance 8 timesteps. Planar LDS (ux plane, uy plane; pitch 52 floats),
// double-buffered, one barrier per step. Each thread owns a 1x4 strip;
// centers + u_{t-1} in registers.
__global__ __launch_bounds__(NTHR)
void cfrp_chunk(const float* __restrict__ lc11, const float* __restrict__ lc22,
                const float* __restrict__ lc12, const float* __restrict__ lc16,
                const float* __restrict__ lc26, const float* __restrict__ lc66,
                const float* __restrict__ rho_p, const float* __restrict__ sig,
                const float* __restrict__ gauss, float* __restrict__ out,
                const float* __restrict__ gcx, const float* __restrict__ gcy,
                const float* __restrict__ gpx, const float* __restrict__ gpy,
                float* __restrict__ ncx, float* __restrict__ ncy,
                float* __restrict__ npx, float* __restrict__ npy,
                int TB)
{
    __shared__ float sls[2][2][PLANE];   // [buf][comp][row*52+col]

    const int tid = (int)threadIdx.x;
    // XCD-affinity: XCD q (= wg&7 round-robin heuristic) owns tile-rows 2q..2q+1.
    const int w  = (int)blockIdx.x;
    const int q  = w & 7;
    const int r_ = w >> 3;                 // 0..31
    const int ti = q * 2 + (r_ >> 4);      // 0..15
    const int tj = r_ & 15;                // 0..15
    const int oi = ti * Tg - Kg;
    const int oj = tj * Tg - Kg;

    // uniform material constants
    const float C11 = fminf(fmaxf(expf(lc11[0]), 1e9f), 1e13f);
    const float C22 = fminf(fmaxf(expf(lc22[0]), 1e9f), 1e13f);
    const float C12 = fminf(fmaxf(expf(lc12[0]), 1e9f), 1e13f);
    const float C16 = fminf(fmaxf(expf(lc16[0]), 1e9f), 1e13f);
    const float C26 = fminf(fmaxf(expf(lc26[0]), 1e9f), 1e13f);
    const float C66 = fminf(fmaxf(expf(lc66[0]), 1e9f), 1e13f);
    const float rh   = rho_p[0];
    const float dt2  = 2.5e-15f;
    const float kk   = dt2 * 1e6f / rh;
    const float kc11 = kk * C11, kc22 = kk * C22, kc66 = kk * C66;
    const float kc16 = kk * C16, kc26 = kk * C26;
    const float kc1266 = kk * (C12 + C66);
    const float kc16x2 = 2.0f * kc16;
    const float kc26x2 = 2.0f * kc26;
    const float gsc = dt2 / rh;

    // ---- stage u_t into both LDS buffers (planar, float4 = 4 cells) ----
    #pragma unroll
    for (int s = 0; s < 2; ++s) {
        const int p    = tid + s * NTHR;       // 0..1151 = 48 rows * 2 comp * 12 quads
        const int rr   = p / 24;
        const int rem  = p - rr * 24;
        const int comp = rem / 12;
        const int qc   = rem - comp * 12;
        const int col4 = qc * 4;
        const int gi   = oi + rr;
        const int gj   = oj + col4;            // multiple of 4; fully in or out
        float4 v = make_float4(0.f, 0.f, 0.f, 0.f);
        if (((unsigned)gi < NXg) && (gj >= 0) && (gj <= (int)NXg - 4)) {
            const float* src = comp ? gcy : gcx;
            v = *(const float4*)&src[gi * NXg + gj];
        }
        const int d = rr * Pg + col4;
        *(float4*)&sls[0][comp][d] = v;
        *(float4*)&sls[1][comp][d] = v;
    }
    // zero the 4-float row pads (cols 48..51), both comps, both buffers
    if (tid < 2 * Eg) {
        const int rr = tid >> 1, comp = tid & 1;
        const int d = rr * Pg + Eg;
        *(float4*)&sls[0][comp][d] = make_float4(0.f, 0.f, 0.f, 0.f);
        *(float4*)&sls[1][comp][d] = make_float4(0.f, 0.f, 0.f, 0.f);
    }

    // ---- per-segment setup (thread owns 1x4 strip) ----
    const int  srow = tid / NSEGR;
    const int  scol = tid - srow * NSEGR;
    const bool act  = (srow >= 1) && (srow <= Eg - 2);
    const int  c0   = scol * 4;
    const int  gi   = oi + srow;
    const int  gj0  = oj + c0;                 // multiple of 4; quad fully in/out
    const int  dC   = srow * Pg + c0;
    const bool in4  = ((unsigned)gi < NXg) && (gj0 >= 0) && (gj0 <= (int)NXg - 4);
    const bool own  = (srow >= Kg) && (srow < Kg + Tg) && (scol >= 2) && (scol <= 9);
    const int  go0  = gi * NXg + gj0;

    float4 pvx = {0,0,0,0}, pvy = {0,0,0,0}, gf4 = {0,0,0,0};
    if (act && in4) {
        pvx = *(const float4*)&gpx[go0];
        pvy = *(const float4*)&gpy[go0];
        const float4 g = *(const float4*)&gauss[go0];
        gf4 = make_float4(g.x * gsc, g.y * gsc, g.z * gsc, g.w * gsc);
    }
    __syncthreads();

    float4 cvx = *(const float4*)&sls[0][0][dC];
    float4 cvy = *(const float4*)&sls[0][1][dC];

    #pragma unroll
    for (int st = 0; st < Kg; ++st) {
        const float fa = sig[TB + st];
        const int cb = st & 1;                 // compile-time (unrolled)
        const float* sx = sls[cb][0];
        const float* sy = sls[cb][1];
        float* tx = sls[cb ^ 1][0];
        float* ty = sls[cb ^ 1][1];

        if (act) {
            const int rN = dC - Pg, rS = dC + Pg;
            const float4 Nx = *(const float4*)&sx[rN];
            const float4 Sx = *(const float4*)&sx[rS];
            const float  nwx = sx[rN - 1], nex = sx[rN + 4];
            const float  swx = sx[rS - 1], sex = sx[rS + 4];
            const float  wx  = sx[dC - 1], ex  = sx[dC + 4];
            const float4 Ny = *(const float4*)&sy[rN];
            const float4 Sy = *(const float4*)&sy[rS];
            const float  nwy = sy[rN - 1], ney = sy[rN + 4];
            const float  swy = sy[rS - 1], sey = sy[rS + 4];
            const float  wy  = sy[dC - 1], ey  = sy[dC + 4];

            float4 nx4, ny4;
            CELL(nx4.x, ny4.x, nwx, Nx.x, Nx.y,  wx,   cvx.x, cvx.y, swx, Sx.x, Sx.y,
                               nwy, Ny.x, Ny.y,  wy,   cvy.x, cvy.y, swy, Sy.x, Sy.y,
                               pvx.x, pvy.x, gf4.x)
            CELL(nx4.y, ny4.y, Nx.x, Nx.y, Nx.z, cvx.x, cvx.y, cvx.z, Sx.x, Sx.y, Sx.z,
                               Ny.x, Ny.y, Ny.z, cvy.x, cvy.y, cvy.z, Sy.x, Sy.y, Sy.z,
                               pvx.y, pvy.y, gf4.y)
            CELL(nx4.z, ny4.z, Nx.y, Nx.z, Nx.w, cvx.y, cvx.z, cvx.w, Sx.y, Sx.z, Sx.w,
                               Ny.y, Ny.z, Ny.w, cvy.y, cvy.z, cvy.w, Sy.y, Sy.z, Sy.w,
                               pvx.z, pvy.z, gf4.z)
            CELL(nx4.w, ny4.w, Nx.z, Nx.w, nex,  cvx.z, cvx.w, ex,    Sx.z, Sx.w, sex,
                               Ny.z, Ny.w, ney,  cvy.z, cvy.w, ey,    Sy.z, Sy.w, sey,
                               pvx.w, pvy.w, gf4.w)

            if (!in4) {       // out-of-domain quad stays 0 (zero padding BC)
                nx4 = make_float4(0.f, 0.f, 0.f, 0.f);
                ny4 = make_float4(0.f, 0.f, 0.f, 0.f);
            }
            pvx = cvx; pvy = cvy;
            cvx = nx4; cvy = ny4;

            *(float4*)&tx[dC] = cvx;
            *(float4*)&ty[dC] = cvy;

            if (((st & 3) == 0) && own) {      // frames at st = 0, 4
                const int fr = (TB + st) >> 2;
                *(float4*)&out[fr * Sg + go0] = cvx;
                *(float4*)&out[(fr + NFRg) * Sg + go0] = cvy;
            }
        }
        __syncthreads();
    }

    // handoff from registers (planar, direct float4)
    if (own) {
        *(float4*)&ncx[go0] = cvx;
        *(float4*)&ncy[go0] = cvy;
        *(float4*)&npx[go0] = pvx;
        *(float4*)&npy[go0] = pvy;
    }
}

extern "C" void kernel_launch(void* const* d_in, const int* in_sizes, int n_in,
                              void* d_out, int out_size, void* d_ws, size_t ws_size,
                              hipStream_t stream) {
    const float* lc11  = (const float*)d_in[0];
    const float* lc22  = (const float*)d_in[1];
    const float* lc12  = (const float*)d_in[2];
    const float* lc16  = (const float*)d_in[3];
    const float* lc26  = (const float*)d_in[4];
    const float* lc66  = (const float*)d_in[5];
    const float* rho_p = (const float*)d_in[6];
    const float* sig   = (const float*)d_in[7];
    const float* gauss = (const float*)d_in[8];
    float* out = (float*)d_out;
    float* ws  = (float*)d_ws;

    // 8 planar planes: A = [cx, cy, px, py], B likewise
    float* Acx = ws;          float* Acy = ws + Sg;
    float* Apx = ws + 2 * Sg; float* Apy = ws + 3 * Sg;
    float* Bcx = ws + 4 * Sg; float* Bcy = ws + 5 * Sg;
    float* Bpx = ws + 6 * Sg; float* Bpy = ws + 7 * Sg;

    hipLaunchKernelGGL(cfrp_init, dim3(512), dim3(512), 0, stream, (float4*)d_ws);

    for (int c = 0; c < NCHUNK; ++c) {
        const float *rcx, *rcy, *rpx, *rpy;
        float *wcx, *wcy, *wpx, *wpy;
        if (c & 1) {
            rcx = Bcx; rcy = Bcy; rpx = Bpx; rpy = Bpy;
            wcx = Acx; wcy = Acy; wpx = Apx; wpy = Apy;
        } else {
            rcx = Acx; rcy = Acy; rpx = Apx; rpy = Apy;
            wcx = Bcx; wcy = Bcy; wpx = Bpx; wpy = Bpy;
        }
        hipLaunchKernelGGL(cfrp_chunk, dim3(256), dim3(NTHR), 0, stream,
                           lc11, lc22, lc12, lc16, lc26, lc66, rho_p, sig,
                           gauss, out, rcx, rcy, rpx, rpy,
                           wcx, wcy, wpx, wpy, c * Kg);
    }
}